// Round 1
// baseline (890.521 us; speedup 1.0000x reference)
//
#include <hip/hip_runtime.h>

// Decoder: y,hn -> h0 -> gx -> 128-step GRU -> logits.  All kernels on `stream`.
// Recurrence: 16 persistent blocks (one per 32-column h-slice), W_hh slice in
// VGPRs, h exchanged via LLC with stamp release/acquire protocol.

typedef __attribute__((ext_vector_type(8))) short           bf8_t;   // MFMA A/B frag (8 bf16)
typedef __attribute__((ext_vector_type(8))) unsigned short  us8_t;
typedef __attribute__((ext_vector_type(4))) unsigned short  us4_t;
typedef __attribute__((ext_vector_type(4))) float           f4_t;    // MFMA C/D frag

__device__ __forceinline__ unsigned short f2bf(float x) {   // RNE fp32->bf16
    unsigned u = __builtin_bit_cast(unsigned, x);
    u += 0x7FFFu + ((u >> 16) & 1u);
    return (unsigned short)(u >> 16);
}
__device__ __forceinline__ float bf2f(unsigned short h) {
    unsigned u = (unsigned)h << 16;
    return __builtin_bit_cast(float, u);
}
__device__ __forceinline__ float sigm(float x) { return 1.0f / (1.0f + __expf(-x)); }

// ---------------- bulk fp32 -> bf16 ----------------
__global__ void k_conv(const float* __restrict__ src, unsigned short* __restrict__ dst, int n4) {
    int i = blockIdx.x * blockDim.x + threadIdx.x;
    int stride = gridDim.x * blockDim.x;
    for (; i < n4; i += stride) {
        f4_t v = ((const f4_t*)src)[i];
        us4_t o;
        o[0] = f2bf(v[0]); o[1] = f2bf(v[1]); o[2] = f2bf(v[2]); o[3] = f2bf(v[3]);
        ((us4_t*)dst)[i] = o;
    }
}

// ---------------- x = bf16(emb[y]) ----------------
__global__ void k_gather(const int* __restrict__ y, const float* __restrict__ emb,
                         unsigned short* __restrict__ xbf) {
    int m = blockIdx.x;            // 2048 rows
    int row = y[m];
    int t = threadIdx.x;           // 128 threads * float4 = 512 cols
    f4_t v = ((const f4_t*)(emb + (size_t)row * 512))[t];
    us4_t o;
    o[0] = f2bf(v[0]); o[1] = f2bf(v[1]); o[2] = f2bf(v[2]); o[3] = f2bf(v[3]);
    ((us4_t*)(xbf + (size_t)m * 512))[t] = o;
}

// ---------------- h0 = hn @ fc_w.T + fc_b (fp32); also zero stamps ----------------
__global__ void k_h0(const float* __restrict__ hn, const float* __restrict__ fc_w,
                     const float* __restrict__ fc_b, float* __restrict__ h0,
                     int* __restrict__ stamps) {
    __shared__ float sh[1024];
    int b = blockIdx.x, t = threadIdx.x;          // 16 blocks x 256 threads
    if (b == 0 && t < 64) stamps[t] = 0;
    for (int i = t; i < 1024; i += 256) sh[i] = hn[b * 1024 + i];
    __syncthreads();
    int j = t;
    float a0 = fc_b[j], a1 = fc_b[j + 256];
    const float* w0 = fc_w + (size_t)j * 1024;
    const float* w1 = fc_w + (size_t)(j + 256) * 1024;
    #pragma unroll 8
    for (int e = 0; e < 1024; e++) { float he = sh[e]; a0 += he * w0[e]; a1 += he * w1[e]; }
    h0[b * 512 + j] = a0;
    h0[b * 512 + j + 256] = a1;
}

// ---------------- C[M][N] = A[M][512](bf16) @ Bt[N][512](bf16)^T + bias (fp32 out) ----
// 128x128 tile, BK=64, 256 threads (4 waves 2x2, 64x64 each), XOR-swizzled LDS.
__launch_bounds__(256)
__global__ void k_gemm(const unsigned short* __restrict__ A, const unsigned short* __restrict__ Bt,
                       const float* __restrict__ bias, float* __restrict__ C, int N) {
    __shared__ unsigned short sA[128 * 64];
    __shared__ unsigned short sB[128 * 64];
    const int m0 = blockIdx.y * 128, n0 = blockIdx.x * 128;
    const int tid = threadIdx.x, lane = tid & 63, wave = tid >> 6;
    const int wm = wave >> 1, wn = wave & 1;
    f4_t acc[4][4] = {};
    for (int ks = 0; ks < 8; ks++) {
        const int k0 = ks * 64;
        #pragma unroll
        for (int t = 0; t < 4; t++) {
            int idx = tid + t * 256;
            int row = idx >> 3, slot = idx & 7;
            int sw = ((slot ^ (row & 7)) << 3);
            *(us8_t*)(&sA[row * 64 + sw]) = *(const us8_t*)(A + (size_t)(m0 + row) * 512 + k0 + slot * 8);
            *(us8_t*)(&sB[row * 64 + sw]) = *(const us8_t*)(Bt + (size_t)(n0 + row) * 512 + k0 + slot * 8);
        }
        __syncthreads();
        #pragma unroll
        for (int kk = 0; kk < 2; kk++) {
            bf8_t af[4], bfr[4];
            #pragma unroll
            for (int mi = 0; mi < 4; mi++) {
                int row = wm * 64 + mi * 16 + (lane & 15);
                int slot = (kk * 4 + (lane >> 4)) ^ (row & 7);
                af[mi] = *(const bf8_t*)(&sA[row * 64 + slot * 8]);
            }
            #pragma unroll
            for (int ni = 0; ni < 4; ni++) {
                int row = wn * 64 + ni * 16 + (lane & 15);
                int slot = (kk * 4 + (lane >> 4)) ^ (row & 7);
                bfr[ni] = *(const bf8_t*)(&sB[row * 64 + slot * 8]);
            }
            #pragma unroll
            for (int mi = 0; mi < 4; mi++)
                #pragma unroll
                for (int ni = 0; ni < 4; ni++)
                    acc[mi][ni] = __builtin_amdgcn_mfma_f32_16x16x32_bf16(af[mi], bfr[ni], acc[mi][ni], 0, 0, 0);
        }
        __syncthreads();
    }
    #pragma unroll
    for (int ni = 0; ni < 4; ni++) {
        int col = n0 + wn * 64 + ni * 16 + (lane & 15);
        float bv = bias[col];
        #pragma unroll
        for (int mi = 0; mi < 4; mi++) {
            int rbase = m0 + wm * 64 + mi * 16 + (lane >> 4) * 4;
            #pragma unroll
            for (int r = 0; r < 4; r++)
                C[(size_t)(rbase + r) * N + col] = acc[mi][ni][r] + bv;
        }
    }
}

// ---------------- persistent GRU scan ----------------
// 16 blocks x 512 threads. Block kb owns h-cols [32kb,32kb+32): W_hh rows
// {g*512+j0..+32 | g=0,1,2} as register MFMA B-frags (waves 0..5, 16 cols each).
// Per step: poll stamps -> acquire fence -> load h[16][512] fp32 -> split bf16
// hi/lo into swizzled LDS -> MFMA pre-acts -> gates (fp32) -> publish slice+stamp.
__launch_bounds__(512, 1)
__global__ void k_rec(const float* __restrict__ W_hh, const float* __restrict__ b_hh,
                      const float* __restrict__ gx, float* __restrict__ hbuf,
                      int* __restrict__ stamps, unsigned short* __restrict__ Hout) {
    const int kb = blockIdx.x;
    const int j0 = kb * 32;
    const int tid = threadIdx.x, lane = tid & 63, wave = tid >> 6;
    __shared__ unsigned short sHi[16 * 512];
    __shared__ unsigned short sLo[16 * 512];
    __shared__ float sPre[96 * 17];          // +1 pad row stride: conflict-free gate reads

    bf8_t wfrag[16];
    if (wave < 6) {
        const int gate = wave >> 1, sub = wave & 1;
        const int wrow = gate * 512 + j0 + sub * 16 + (lane & 15);
        const f4_t* wp4 = (const f4_t*)(W_hh + (size_t)wrow * 512);
        #pragma unroll
        for (int kk = 0; kk < 16; kk++) {
            f4_t v0 = wp4[kk * 8 + (lane >> 4) * 2];
            f4_t v1 = wp4[kk * 8 + (lane >> 4) * 2 + 1];
            bf8_t f;
            f[0] = (short)f2bf(v0[0]); f[1] = (short)f2bf(v0[1]);
            f[2] = (short)f2bf(v0[2]); f[3] = (short)f2bf(v0[3]);
            f[4] = (short)f2bf(v1[0]); f[5] = (short)f2bf(v1[1]);
            f[6] = (short)f2bf(v1[2]); f[7] = (short)f2bf(v1[3]);
            wfrag[kk] = f;
        }
    }

    const int b_ = tid >> 5, jj = tid & 31;   // (batch, column) owned by this thread
    const float brv = b_hh[j0 + jj], bzv = b_hh[512 + j0 + jj], bnv = b_hh[1024 + j0 + jj];
    float h_reg = hbuf[b_ * 512 + j0 + jj];   // h0

    for (int s = 1; s <= 128; s++) {
        if (wave == 0) {                      // wait for everyone's h[s-1]
            const int target = s - 1;
            int spins = 0; bool ok;
            do {
                int st = target;
                if (lane < 16) st = __hip_atomic_load(&stamps[lane], __ATOMIC_RELAXED, __HIP_MEMORY_SCOPE_AGENT);
                ok = (st >= target);
                if (!ok) __builtin_amdgcn_s_sleep(1);
                if (++spins > (1 << 22)) break;       // hang guard
            } while (!__all(ok));
        }
        __syncthreads();
        __builtin_amdgcn_fence(__ATOMIC_ACQUIRE, "agent");

        // stage h[s-1] -> LDS as bf16 hi/lo (Dekker split), XOR-swizzled
        const float* hsrc = hbuf + ((s - 1) & 1) * 8192;
        #pragma unroll
        for (int t = 0; t < 4; t++) {
            int idx4 = tid + t * 512;                 // 2048 float4s
            int row = idx4 >> 7, c4 = idx4 & 127;
            f4_t v = *(const f4_t*)(hsrc + idx4 * 4);
            us4_t hi, lo;
            #pragma unroll
            for (int i = 0; i < 4; i++) {
                unsigned short h = f2bf(v[i]);
                hi[i] = h;
                lo[i] = f2bf(v[i] - bf2f(h));
            }
            int base = row * 512 + (((c4 >> 1) ^ (row & 7)) << 3) + (c4 & 1) * 4;
            *(us4_t*)(&sHi[base]) = hi;
            *(us4_t*)(&sLo[base]) = lo;
        }
        __syncthreads();

        if (wave < 6) {                       // pre = h @ Wslice.T  (hi+lo accumulate)
            f4_t acc = {0.f, 0.f, 0.f, 0.f};
            const int m = lane & 15;
            #pragma unroll
            for (int kk = 0; kk < 16; kk++) {
                int off = m * 512 + (((kk * 4 + (lane >> 4)) ^ (m & 7)) << 3);
                bf8_t ahi = *(const bf8_t*)(&sHi[off]);
                bf8_t alo = *(const bf8_t*)(&sLo[off]);
                acc = __builtin_amdgcn_mfma_f32_16x16x32_bf16(ahi, wfrag[kk], acc, 0, 0, 0);
                acc = __builtin_amdgcn_mfma_f32_16x16x32_bf16(alo, wfrag[kk], acc, 0, 0, 0);
            }
            const int n = wave * 16 + (lane & 15);
            #pragma unroll
            for (int r = 0; r < 4; r++) sPre[n * 17 + (lane >> 4) * 4 + r] = acc[r];
        }
        __syncthreads();

        // gates: thread owns (b_, jj)
        const float* gxp = gx + (size_t)(b_ * 128 + (s - 1)) * 1536 + j0 + jj;
        float gr = gxp[0], gz = gxp[512], gn = gxp[1024];
        float r = sigm(gr + sPre[jj * 17 + b_] + brv);
        float z = sigm(gz + sPre[(32 + jj) * 17 + b_] + bzv);
        float nn = tanhf(gn + r * (sPre[(64 + jj) * 17 + b_] + bnv));
        float hnew = (1.f - z) * nn + z * h_reg;
        h_reg = hnew;
        __hip_atomic_store(&hbuf[(s & 1) * 8192 + b_ * 512 + j0 + jj], hnew,
                           __ATOMIC_RELAXED, __HIP_MEMORY_SCOPE_AGENT);
        Hout[(size_t)(b_ * 128 + (s - 1)) * 512 + j0 + jj] = f2bf(hnew);
        __syncthreads();                      // all waves' stores drained (vmcnt) pre-barrier
        if (tid == 0) {
            __threadfence();                  // agent release: flush to LLC
            __hip_atomic_store(&stamps[kb], s, __ATOMIC_RELEASE, __HIP_MEMORY_SCOPE_AGENT);
        }
    }
}

extern "C" void kernel_launch(void* const* d_in, const int* in_sizes, int n_in,
                              void* d_out, int out_size, void* d_ws, size_t ws_size,
                              hipStream_t stream) {
    const int*   y      = (const int*)  d_in[0];
    const float* hn     = (const float*)d_in[1];
    const float* emb    = (const float*)d_in[2];
    const float* W_ih   = (const float*)d_in[3];
    const float* W_hh   = (const float*)d_in[4];
    const float* b_ih   = (const float*)d_in[5];
    const float* b_hh   = (const float*)d_in[6];
    const float* fc_w   = (const float*)d_in[7];
    const float* fc_b   = (const float*)d_in[8];
    const float* pred_w = (const float*)d_in[9];
    const float* pred_b = (const float*)d_in[10];
    float* out = (float*)d_out;

    char* ws = (char*)d_ws;
    size_t off = 0;
    auto alloc = [&](size_t bytes) { void* p = ws + off; off = (off + bytes + 255) & ~(size_t)255; return p; };
    float*          hbuf   = (float*)          alloc(2 * 16 * 512 * 4);       // h double buffer
    int*            stamps = (int*)            alloc(256);
    float*          gx     = (float*)          alloc((size_t)2048 * 1536 * 4);
    unsigned short* Hout   = (unsigned short*) alloc((size_t)2048 * 512 * 2);
    unsigned short* xbf    = (unsigned short*) alloc((size_t)2048 * 512 * 2);
    unsigned short* wihbf  = (unsigned short*) alloc((size_t)1536 * 512 * 2);
    unsigned short* pwbf   = (unsigned short*) alloc((size_t)32000 * 512 * 2);
    (void)ws_size; (void)in_sizes; (void)n_in; (void)out_size;               // ~51 MB used

    k_conv  <<<4096, 256, 0, stream>>>(pred_w, pwbf, 32000 * 512 / 4);
    k_conv  <<<512,  256, 0, stream>>>(W_ih,  wihbf, 1536 * 512 / 4);
    k_gather<<<2048, 128, 0, stream>>>(y, emb, xbf);
    k_h0    <<<16,   256, 0, stream>>>(hn, fc_w, fc_b, hbuf, stamps);
    dim3 gG(12, 16);
    k_gemm  <<<gG, 256, 0, stream>>>(xbf, wihbf, b_ih, gx, 1536);
    k_rec   <<<16, 512, 0, stream>>>(W_hh, b_hh, gx, hbuf, stamps, Hout);
    dim3 gP(250, 16);
    k_gemm  <<<gP, 256, 0, stream>>>(Hout, pwbf, pred_b, out, 32000);
}

// Round 2
// 688.592 us; speedup vs baseline: 1.2932x; 1.2932x over previous
//
#include <hip/hip_runtime.h>

// Decoder: y,hn -> h0 -> gx -> 128-step GRU -> logits.  All kernels on `stream`.
// Recurrence: 16 persistent blocks (one per 32-column h-slice), W_hh slice in
// VGPRs, h exchanged through the LLC via sc0 sc1 (cache-bypassing) accesses +
// per-block stamp release/acquire. NO cache-wide fences (buffer_inv/wbl2) --
// that was 5.1 us/step in round 1.

typedef __attribute__((ext_vector_type(8))) short           bf8_t;   // MFMA A/B frag (8 bf16)
typedef __attribute__((ext_vector_type(8))) unsigned short  us8_t;
typedef __attribute__((ext_vector_type(4))) unsigned short  us4_t;
typedef __attribute__((ext_vector_type(4))) float           f4_t;    // MFMA C/D frag

__device__ __forceinline__ unsigned short f2bf(float x) {   // RNE fp32->bf16
    unsigned u = __builtin_bit_cast(unsigned, x);
    u += 0x7FFFu + ((u >> 16) & 1u);
    return (unsigned short)(u >> 16);
}
__device__ __forceinline__ float bf2f(unsigned short h) {
    unsigned u = (unsigned)h << 16;
    return __builtin_bit_cast(float, u);
}
__device__ __forceinline__ float sigm(float x) { return 1.0f / (1.0f + __expf(-x)); }

// ---- LLC-coherent (sc0 sc1 = bypass L1+L2, hit coherence point) accessors ----
__device__ __forceinline__ void llc_store_f32(float* p, float v) {
    asm volatile("global_store_dword %0, %1, off sc0 sc1" :: "v"(p), "v"(v) : "memory");
}
__device__ __forceinline__ void llc_store_i32(int* p, int v) {
    asm volatile("global_store_dword %0, %1, off sc0 sc1" :: "v"(p), "v"(v) : "memory");
}
__device__ __forceinline__ int llc_poll_i32(const int* p) {   // load + waitcnt in one block
    int r;
    asm volatile("global_load_dword %0, %1, off sc0 sc1\n\t"
                 "s_waitcnt vmcnt(0)"
                 : "=&v"(r) : "v"(p) : "memory");
    return r;
}

// ---------------- bulk fp32 -> bf16 ----------------
__global__ void k_conv(const float* __restrict__ src, unsigned short* __restrict__ dst, int n4) {
    int i = blockIdx.x * blockDim.x + threadIdx.x;
    int stride = gridDim.x * blockDim.x;
    for (; i < n4; i += stride) {
        f4_t v = ((const f4_t*)src)[i];
        us4_t o;
        o[0] = f2bf(v[0]); o[1] = f2bf(v[1]); o[2] = f2bf(v[2]); o[3] = f2bf(v[3]);
        ((us4_t*)dst)[i] = o;
    }
}

// ---------------- x = bf16(emb[y]) ----------------
__global__ void k_gather(const int* __restrict__ y, const float* __restrict__ emb,
                         unsigned short* __restrict__ xbf) {
    int m = blockIdx.x;            // 2048 rows
    int row = y[m];
    int t = threadIdx.x;           // 128 threads * float4 = 512 cols
    f4_t v = ((const f4_t*)(emb + (size_t)row * 512))[t];
    us4_t o;
    o[0] = f2bf(v[0]); o[1] = f2bf(v[1]); o[2] = f2bf(v[2]); o[3] = f2bf(v[3]);
    ((us4_t*)(xbf + (size_t)m * 512))[t] = o;
}

// ---------------- h0 = hn @ fc_w.T + fc_b (fp32); also zero stamps ----------------
__global__ void k_h0(const float* __restrict__ hn, const float* __restrict__ fc_w,
                     const float* __restrict__ fc_b, float* __restrict__ h0,
                     int* __restrict__ stamps) {
    __shared__ float sh[1024];
    int b = blockIdx.x, t = threadIdx.x;          // 16 blocks x 256 threads
    if (b == 0 && t < 64) stamps[t] = 0;
    for (int i = t; i < 1024; i += 256) sh[i] = hn[b * 1024 + i];
    __syncthreads();
    int j = t;
    float a0 = fc_b[j], a1 = fc_b[j + 256];
    const float* w0 = fc_w + (size_t)j * 1024;
    const float* w1 = fc_w + (size_t)(j + 256) * 1024;
    #pragma unroll 8
    for (int e = 0; e < 1024; e++) { float he = sh[e]; a0 += he * w0[e]; a1 += he * w1[e]; }
    h0[b * 512 + j] = a0;
    h0[b * 512 + j + 256] = a1;
}

// ---------------- C[M][N] = A[M][512](bf16) @ Bt[N][512](bf16)^T + bias (fp32 out) ----
// 128x128 tile, BK=64, 256 threads (4 waves 2x2, 64x64 each), XOR-swizzled LDS.
__launch_bounds__(256)
__global__ void k_gemm(const unsigned short* __restrict__ A, const unsigned short* __restrict__ Bt,
                       const float* __restrict__ bias, float* __restrict__ C, int N) {
    __shared__ unsigned short sA[128 * 64];
    __shared__ unsigned short sB[128 * 64];
    const int m0 = blockIdx.y * 128, n0 = blockIdx.x * 128;
    const int tid = threadIdx.x, lane = tid & 63, wave = tid >> 6;
    const int wm = wave >> 1, wn = wave & 1;
    f4_t acc[4][4] = {};
    for (int ks = 0; ks < 8; ks++) {
        const int k0 = ks * 64;
        #pragma unroll
        for (int t = 0; t < 4; t++) {
            int idx = tid + t * 256;
            int row = idx >> 3, slot = idx & 7;
            int sw = ((slot ^ (row & 7)) << 3);
            *(us8_t*)(&sA[row * 64 + sw]) = *(const us8_t*)(A + (size_t)(m0 + row) * 512 + k0 + slot * 8);
            *(us8_t*)(&sB[row * 64 + sw]) = *(const us8_t*)(Bt + (size_t)(n0 + row) * 512 + k0 + slot * 8);
        }
        __syncthreads();
        #pragma unroll
        for (int kk = 0; kk < 2; kk++) {
            bf8_t af[4], bfr[4];
            #pragma unroll
            for (int mi = 0; mi < 4; mi++) {
                int row = wm * 64 + mi * 16 + (lane & 15);
                int slot = (kk * 4 + (lane >> 4)) ^ (row & 7);
                af[mi] = *(const bf8_t*)(&sA[row * 64 + slot * 8]);
            }
            #pragma unroll
            for (int ni = 0; ni < 4; ni++) {
                int row = wn * 64 + ni * 16 + (lane & 15);
                int slot = (kk * 4 + (lane >> 4)) ^ (row & 7);
                bfr[ni] = *(const bf8_t*)(&sB[row * 64 + slot * 8]);
            }
            #pragma unroll
            for (int mi = 0; mi < 4; mi++)
                #pragma unroll
                for (int ni = 0; ni < 4; ni++)
                    acc[mi][ni] = __builtin_amdgcn_mfma_f32_16x16x32_bf16(af[mi], bfr[ni], acc[mi][ni], 0, 0, 0);
        }
        __syncthreads();
    }
    #pragma unroll
    for (int ni = 0; ni < 4; ni++) {
        int col = n0 + wn * 64 + ni * 16 + (lane & 15);
        float bv = bias[col];
        #pragma unroll
        for (int mi = 0; mi < 4; mi++) {
            int rbase = m0 + wm * 64 + mi * 16 + (lane >> 4) * 4;
            #pragma unroll
            for (int r = 0; r < 4; r++)
                C[(size_t)(rbase + r) * N + col] = acc[mi][ni][r] + bv;
        }
    }
}

// ---------------- persistent GRU scan ----------------
// 16 blocks x 512 threads. Block kb owns h-cols [32kb,32kb+32): W_hh rows
// {g*512+j0..+32 | g=0,1,2} as register MFMA B-frags (waves 0..5, 16 cols each).
// Per step: all-waves poll stamps (sc0sc1) -> load h (sc0sc1, LLC) -> bf16
// hi/lo Dekker split into swizzled LDS -> MFMA pre-acts -> gates (fp32) ->
// publish slice (sc0sc1 + vmcnt(0) + barrier) -> stamp.
__launch_bounds__(512, 1)
__global__ void k_rec(const float* __restrict__ W_hh, const float* __restrict__ b_hh,
                      const float* __restrict__ gx, float* __restrict__ hbuf,
                      int* __restrict__ stamps, unsigned short* __restrict__ Hout) {
    const int kb = blockIdx.x;
    const int j0 = kb * 32;
    const int tid = threadIdx.x, lane = tid & 63, wave = tid >> 6;
    __shared__ unsigned short sHi[16 * 512];
    __shared__ unsigned short sLo[16 * 512];
    __shared__ float sPre[96 * 17];          // +1 pad row stride: conflict-free gate reads

    bf8_t wfrag[16];
    if (wave < 6) {
        const int gate = wave >> 1, sub = wave & 1;
        const int wrow = gate * 512 + j0 + sub * 16 + (lane & 15);
        const f4_t* wp4 = (const f4_t*)(W_hh + (size_t)wrow * 512);
        #pragma unroll
        for (int kk = 0; kk < 16; kk++) {
            f4_t v0 = wp4[kk * 8 + (lane >> 4) * 2];
            f4_t v1 = wp4[kk * 8 + (lane >> 4) * 2 + 1];
            bf8_t f;
            f[0] = (short)f2bf(v0[0]); f[1] = (short)f2bf(v0[1]);
            f[2] = (short)f2bf(v0[2]); f[3] = (short)f2bf(v0[3]);
            f[4] = (short)f2bf(v1[0]); f[5] = (short)f2bf(v1[1]);
            f[6] = (short)f2bf(v1[2]); f[7] = (short)f2bf(v1[3]);
            wfrag[kk] = f;
        }
    }

    const int b_ = tid >> 5, jj = tid & 31;   // (batch, column) owned by this thread
    const float brv = b_hh[j0 + jj], bzv = b_hh[512 + j0 + jj], bnv = b_hh[1024 + j0 + jj];
    float h_reg = hbuf[b_ * 512 + j0 + jj];   // h0

    for (int s = 1; s <= 128; s++) {
        // gx prefetch (normal cached loads) -- latency hides under the poll
        const float* gxp = gx + (size_t)(b_ * 128 + (s - 1)) * 1536 + j0 + jj;
        float gr = gxp[0], gz = gxp[512], gn = gxp[1024];

        {   // all waves poll all 16 stamps (lanes 0..15); no barrier needed after
            const int target = s - 1;
            int spins = 0; bool ok;
            do {
                int st = target;
                if (lane < 16) st = llc_poll_i32(&stamps[lane]);
                ok = (st >= target);
                if (!ok) __builtin_amdgcn_s_sleep(1);
            } while (!__all(ok) && ++spins < (1 << 20));   // hang guard
        }

        // load h[s-1] straight from LLC: 4 x dwordx4 per thread, waitcnt inside
        // the asm so the compiler's value-ready model matches hardware.
        const float* hsrc = hbuf + ((s - 1) & 1) * 8192;
        f4_t hv0, hv1, hv2, hv3;
        {
            const float* p0 = hsrc + (size_t)tid * 4;
            const float* p1 = hsrc + (size_t)(tid + 512) * 4;
            const float* p2 = hsrc + (size_t)(tid + 1024) * 4;
            const float* p3 = hsrc + (size_t)(tid + 1536) * 4;
            asm volatile(
                "global_load_dwordx4 %0, %4, off sc0 sc1\n\t"
                "global_load_dwordx4 %1, %5, off sc0 sc1\n\t"
                "global_load_dwordx4 %2, %6, off sc0 sc1\n\t"
                "global_load_dwordx4 %3, %7, off sc0 sc1\n\t"
                "s_waitcnt vmcnt(0)"
                : "=&v"(hv0), "=&v"(hv1), "=&v"(hv2), "=&v"(hv3)
                : "v"(p0), "v"(p1), "v"(p2), "v"(p3)
                : "memory");
        }
        __builtin_amdgcn_sched_barrier(0);

        // stage -> LDS as bf16 hi/lo (Dekker split), XOR-swizzled
        {
            f4_t hv[4] = {hv0, hv1, hv2, hv3};
            #pragma unroll
            for (int t = 0; t < 4; t++) {
                int idx4 = tid + t * 512;                 // 2048 float4s
                int row = idx4 >> 7, c4 = idx4 & 127;
                us4_t hi, lo;
                #pragma unroll
                for (int i = 0; i < 4; i++) {
                    unsigned short h = f2bf(hv[t][i]);
                    hi[i] = h;
                    lo[i] = f2bf(hv[t][i] - bf2f(h));
                }
                int base = row * 512 + (((c4 >> 1) ^ (row & 7)) << 3) + (c4 & 1) * 4;
                *(us4_t*)(&sHi[base]) = hi;
                *(us4_t*)(&sLo[base]) = lo;
            }
        }
        __syncthreads();

        if (wave < 6) {                       // pre = h @ Wslice.T  (hi+lo accumulate)
            f4_t acc = {0.f, 0.f, 0.f, 0.f};
            const int m = lane & 15;
            #pragma unroll
            for (int kk = 0; kk < 16; kk++) {
                int off = m * 512 + (((kk * 4 + (lane >> 4)) ^ (m & 7)) << 3);
                bf8_t ahi = *(const bf8_t*)(&sHi[off]);
                bf8_t alo = *(const bf8_t*)(&sLo[off]);
                acc = __builtin_amdgcn_mfma_f32_16x16x32_bf16(ahi, wfrag[kk], acc, 0, 0, 0);
                acc = __builtin_amdgcn_mfma_f32_16x16x32_bf16(alo, wfrag[kk], acc, 0, 0, 0);
            }
            const int n = wave * 16 + (lane & 15);
            #pragma unroll
            for (int r = 0; r < 4; r++) sPre[n * 17 + (lane >> 4) * 4 + r] = acc[r];
        }
        __syncthreads();

        // gates: thread owns (b_, jj)
        float r = sigm(gr + sPre[jj * 17 + b_] + brv);
        float z = sigm(gz + sPre[(32 + jj) * 17 + b_] + bzv);
        float nn = tanhf(gn + r * (sPre[(64 + jj) * 17 + b_] + bnv));
        float hnew = (1.f - z) * nn + z * h_reg;
        h_reg = hnew;

        // publish: sc0sc1 store -> per-wave drain -> barrier -> stamp
        llc_store_f32(&hbuf[(s & 1) * 8192 + b_ * 512 + j0 + jj], hnew);
        asm volatile("s_waitcnt vmcnt(0)" ::: "memory");
        __syncthreads();
        if (tid == 0) llc_store_i32(&stamps[kb], s);
        Hout[(size_t)(b_ * 128 + (s - 1)) * 512 + j0 + jj] = f2bf(hnew);  // overlaps next poll
    }
}

extern "C" void kernel_launch(void* const* d_in, const int* in_sizes, int n_in,
                              void* d_out, int out_size, void* d_ws, size_t ws_size,
                              hipStream_t stream) {
    const int*   y      = (const int*)  d_in[0];
    const float* hn     = (const float*)d_in[1];
    const float* emb    = (const float*)d_in[2];
    const float* W_ih   = (const float*)d_in[3];
    const float* W_hh   = (const float*)d_in[4];
    const float* b_ih   = (const float*)d_in[5];
    const float* b_hh   = (const float*)d_in[6];
    const float* fc_w   = (const float*)d_in[7];
    const float* fc_b   = (const float*)d_in[8];
    const float* pred_w = (const float*)d_in[9];
    const float* pred_b = (const float*)d_in[10];
    float* out = (float*)d_out;

    char* ws = (char*)d_ws;
    size_t off = 0;
    auto alloc = [&](size_t bytes) { void* p = ws + off; off = (off + bytes + 255) & ~(size_t)255; return p; };
    float*          hbuf   = (float*)          alloc(2 * 16 * 512 * 4);       // h double buffer
    int*            stamps = (int*)            alloc(256);
    float*          gx     = (float*)          alloc((size_t)2048 * 1536 * 4);
    unsigned short* Hout   = (unsigned short*) alloc((size_t)2048 * 512 * 2);
    unsigned short* xbf    = (unsigned short*) alloc((size_t)2048 * 512 * 2);
    unsigned short* wihbf  = (unsigned short*) alloc((size_t)1536 * 512 * 2);
    unsigned short* pwbf   = (unsigned short*) alloc((size_t)32000 * 512 * 2);
    (void)ws_size; (void)in_sizes; (void)n_in; (void)out_size;               // ~51 MB used

    k_conv  <<<4096, 256, 0, stream>>>(pred_w, pwbf, 32000 * 512 / 4);
    k_conv  <<<512,  256, 0, stream>>>(W_ih,  wihbf, 1536 * 512 / 4);
    k_gather<<<2048, 128, 0, stream>>>(y, emb, xbf);
    k_h0    <<<16,   256, 0, stream>>>(hn, fc_w, fc_b, hbuf, stamps);
    dim3 gG(12, 16);
    k_gemm  <<<gG, 256, 0, stream>>>(xbf, wihbf, b_ih, gx, 1536);
    k_rec   <<<16, 512, 0, stream>>>(W_hh, b_hh, gx, hbuf, stamps, Hout);
    dim3 gP(250, 16);
    k_gemm  <<<gP, 256, 0, stream>>>(Hout, pwbf, pred_b, out, 32000);
}

// Round 3
// 572.469 us; speedup vs baseline: 1.5556x; 1.2028x over previous
//
#include <hip/hip_runtime.h>

// Decoder: y,hn -> h0 -> gx -> 128-step GRU -> logits.  All kernels on `stream`.
// Recurrence: 16 persistent blocks (one per 32-column h-slice), W_hh slice in
// VGPRs. h exchange: per-step dedicated buffers hbuf[s][16][512], sentinel
// (-NaN) pre-filled; writers do one-way sc0sc1 stores, readers POLL THE DATA
// (detect==load, single LLC round trip). No stamps, no fences, no store drain.

typedef __attribute__((ext_vector_type(8))) short           bf8_t;   // MFMA A/B frag (8 bf16)
typedef __attribute__((ext_vector_type(8))) unsigned short  us8_t;
typedef __attribute__((ext_vector_type(4))) unsigned short  us4_t;
typedef __attribute__((ext_vector_type(4))) float           f4_t;    // MFMA C/D frag
typedef __attribute__((ext_vector_type(4))) unsigned int    u4_t;

#define SENT 0xFFFFFFFFu   // -NaN: unreachable by finite GRU arithmetic

__device__ __forceinline__ unsigned short f2bf(float x) {   // RNE fp32->bf16
    unsigned u = __builtin_bit_cast(unsigned, x);
    u += 0x7FFFu + ((u >> 16) & 1u);
    return (unsigned short)(u >> 16);
}
__device__ __forceinline__ float bf2f(unsigned short h) {
    unsigned u = (unsigned)h << 16;
    return __builtin_bit_cast(float, u);
}
__device__ __forceinline__ float sigm(float x) { return 1.0f / (1.0f + __expf(-x)); }

// ---- LLC-coherent (sc0 sc1 = bypass L1+L2, hit coherence point) accessors ----
__device__ __forceinline__ void llc_store_f32(float* p, float v) {
    asm volatile("global_store_dword %0, %1, off sc0 sc1" :: "v"(p), "v"(v) : "memory");
}

// ---------------- sentinel fill: hbuf[0..128][16][512] ----------------
__global__ void k_fill(unsigned int* __restrict__ p) {
    int i = blockIdx.x * blockDim.x + threadIdx.x;   // 264192 u4s = 129*8192 floats
    u4_t v = {SENT, SENT, SENT, SENT};
    ((u4_t*)p)[i] = v;
}

// ---------------- bulk fp32 -> bf16 ----------------
__global__ void k_conv(const float* __restrict__ src, unsigned short* __restrict__ dst, int n4) {
    int i = blockIdx.x * blockDim.x + threadIdx.x;
    int stride = gridDim.x * blockDim.x;
    for (; i < n4; i += stride) {
        f4_t v = ((const f4_t*)src)[i];
        us4_t o;
        o[0] = f2bf(v[0]); o[1] = f2bf(v[1]); o[2] = f2bf(v[2]); o[3] = f2bf(v[3]);
        ((us4_t*)dst)[i] = o;
    }
}

// ---------------- x = bf16(emb[y]) ----------------
__global__ void k_gather(const int* __restrict__ y, const float* __restrict__ emb,
                         unsigned short* __restrict__ xbf) {
    int m = blockIdx.x;            // 2048 rows
    int row = y[m];
    int t = threadIdx.x;           // 128 threads * float4 = 512 cols
    f4_t v = ((const f4_t*)(emb + (size_t)row * 512))[t];
    us4_t o;
    o[0] = f2bf(v[0]); o[1] = f2bf(v[1]); o[2] = f2bf(v[2]); o[3] = f2bf(v[3]);
    ((us4_t*)(xbf + (size_t)m * 512))[t] = o;
}

// ---------------- h0 = hn @ fc_w.T + fc_b (fp32, full overwrite of hbuf[0]) ----
__global__ void k_h0(const float* __restrict__ hn, const float* __restrict__ fc_w,
                     const float* __restrict__ fc_b, float* __restrict__ h0) {
    __shared__ float sh[1024];
    int b = blockIdx.x, t = threadIdx.x;          // 16 blocks x 256 threads
    for (int i = t; i < 1024; i += 256) sh[i] = hn[b * 1024 + i];
    __syncthreads();
    int j = t;
    float a0 = fc_b[j], a1 = fc_b[j + 256];
    const float* w0 = fc_w + (size_t)j * 1024;
    const float* w1 = fc_w + (size_t)(j + 256) * 1024;
    #pragma unroll 8
    for (int e = 0; e < 1024; e++) { float he = sh[e]; a0 += he * w0[e]; a1 += he * w1[e]; }
    h0[b * 512 + j] = a0;
    h0[b * 512 + j + 256] = a1;
}

// ---------------- C[M][N] = A[M][512](bf16) @ Bt[N][512](bf16)^T + bias (fp32 out) ----
// 128x128 tile, BK=64, 256 threads (4 waves 2x2, 64x64 each), XOR-swizzled LDS.
__launch_bounds__(256)
__global__ void k_gemm(const unsigned short* __restrict__ A, const unsigned short* __restrict__ Bt,
                       const float* __restrict__ bias, float* __restrict__ C, int N) {
    __shared__ unsigned short sA[128 * 64];
    __shared__ unsigned short sB[128 * 64];
    const int m0 = blockIdx.y * 128, n0 = blockIdx.x * 128;
    const int tid = threadIdx.x, lane = tid & 63, wave = tid >> 6;
    const int wm = wave >> 1, wn = wave & 1;
    f4_t acc[4][4] = {};
    for (int ks = 0; ks < 8; ks++) {
        const int k0 = ks * 64;
        #pragma unroll
        for (int t = 0; t < 4; t++) {
            int idx = tid + t * 256;
            int row = idx >> 3, slot = idx & 7;
            int sw = ((slot ^ (row & 7)) << 3);
            *(us8_t*)(&sA[row * 64 + sw]) = *(const us8_t*)(A + (size_t)(m0 + row) * 512 + k0 + slot * 8);
            *(us8_t*)(&sB[row * 64 + sw]) = *(const us8_t*)(Bt + (size_t)(n0 + row) * 512 + k0 + slot * 8);
        }
        __syncthreads();
        #pragma unroll
        for (int kk = 0; kk < 2; kk++) {
            bf8_t af[4], bfr[4];
            #pragma unroll
            for (int mi = 0; mi < 4; mi++) {
                int row = wm * 64 + mi * 16 + (lane & 15);
                int slot = (kk * 4 + (lane >> 4)) ^ (row & 7);
                af[mi] = *(const bf8_t*)(&sA[row * 64 + slot * 8]);
            }
            #pragma unroll
            for (int ni = 0; ni < 4; ni++) {
                int row = wn * 64 + ni * 16 + (lane & 15);
                int slot = (kk * 4 + (lane >> 4)) ^ (row & 7);
                bfr[ni] = *(const bf8_t*)(&sB[row * 64 + slot * 8]);
            }
            #pragma unroll
            for (int mi = 0; mi < 4; mi++)
                #pragma unroll
                for (int ni = 0; ni < 4; ni++)
                    acc[mi][ni] = __builtin_amdgcn_mfma_f32_16x16x32_bf16(af[mi], bfr[ni], acc[mi][ni], 0, 0, 0);
        }
        __syncthreads();
    }
    #pragma unroll
    for (int ni = 0; ni < 4; ni++) {
        int col = n0 + wn * 64 + ni * 16 + (lane & 15);
        float bv = bias[col];
        #pragma unroll
        for (int mi = 0; mi < 4; mi++) {
            int rbase = m0 + wm * 64 + mi * 16 + (lane >> 4) * 4;
            #pragma unroll
            for (int r = 0; r < 4; r++)
                C[(size_t)(rbase + r) * N + col] = acc[mi][ni][r] + bv;
        }
    }
}

// ---------------- persistent GRU scan ----------------
// 16 blocks x 512 threads. Block kb owns h-cols [32kb,32kb+32): W_hh rows
// {g*512+j0..+32 | g=0,1,2} as register MFMA B-frags (waves 0..5, 16 cols each).
// Per step: poll h[s-1] data until own 16 dwords != SENT (detect==load) ->
// bf16 hi/lo Dekker split into swizzled LDS -> MFMA pre-acts -> gates (fp32)
// -> one-way sc0sc1 publish of own slice into hbuf[s]. Two barriers/step.
__launch_bounds__(512, 1)
__global__ void k_rec(const float* __restrict__ W_hh, const float* __restrict__ b_hh,
                      const float* __restrict__ gx, float* __restrict__ hbuf,
                      unsigned short* __restrict__ Hout) {
    const int kb = blockIdx.x;
    const int j0 = kb * 32;
    const int tid = threadIdx.x, lane = tid & 63, wave = tid >> 6;
    __shared__ unsigned short sHi[16 * 512];
    __shared__ unsigned short sLo[16 * 512];
    __shared__ float sPre[96 * 17];          // +1 pad row stride: conflict-free gate reads

    bf8_t wfrag[16];
    if (wave < 6) {
        const int gate = wave >> 1, sub = wave & 1;
        const int wrow = gate * 512 + j0 + sub * 16 + (lane & 15);
        const f4_t* wp4 = (const f4_t*)(W_hh + (size_t)wrow * 512);
        #pragma unroll
        for (int kk = 0; kk < 16; kk++) {
            f4_t v0 = wp4[kk * 8 + (lane >> 4) * 2];
            f4_t v1 = wp4[kk * 8 + (lane >> 4) * 2 + 1];
            bf8_t f;
            f[0] = (short)f2bf(v0[0]); f[1] = (short)f2bf(v0[1]);
            f[2] = (short)f2bf(v0[2]); f[3] = (short)f2bf(v0[3]);
            f[4] = (short)f2bf(v1[0]); f[5] = (short)f2bf(v1[1]);
            f[6] = (short)f2bf(v1[2]); f[7] = (short)f2bf(v1[3]);
            wfrag[kk] = f;
        }
    }

    const int b_ = tid >> 5, jj = tid & 31;   // (batch, column) owned by this thread
    const float brv = b_hh[j0 + jj], bzv = b_hh[512 + j0 + jj], bnv = b_hh[1024 + j0 + jj];
    float h_reg = hbuf[b_ * 512 + j0 + jj];   // h0 (hbuf[0], fully written by k_h0)

    for (int s = 1; s <= 128; s++) {
        // gx prefetch (normal cached loads) -- latency hides under the poll
        const float* gxp = gx + (size_t)(b_ * 128 + (s - 1)) * 1536 + j0 + jj;
        float gr = gxp[0], gz = gxp[512], gn = gxp[1024];

        // poll h[s-1]: this thread's 4 f4s (all from one writer block, col c4
        // fixed, 4 batch rows). Detect == load: one LLC round trip.
        const float* hsrc = hbuf + (size_t)(s - 1) * 8192;
        const float* p0 = hsrc + (size_t)tid * 4;
        const float* p1 = hsrc + (size_t)(tid + 512) * 4;
        const float* p2 = hsrc + (size_t)(tid + 1024) * 4;
        const float* p3 = hsrc + (size_t)(tid + 1536) * 4;
        f4_t hv0, hv1, hv2, hv3;
        int spins = 0;
        bool ok;
        do {
            asm volatile(
                "global_load_dwordx4 %0, %4, off sc0 sc1\n\t"
                "global_load_dwordx4 %1, %5, off sc0 sc1\n\t"
                "global_load_dwordx4 %2, %6, off sc0 sc1\n\t"
                "global_load_dwordx4 %3, %7, off sc0 sc1\n\t"
                "s_waitcnt vmcnt(0)"
                : "=&v"(hv0), "=&v"(hv1), "=&v"(hv2), "=&v"(hv3)
                : "v"(p0), "v"(p1), "v"(p2), "v"(p3)
                : "memory");
            ok = true;
            #pragma unroll
            for (int i = 0; i < 4; i++) {
                ok = ok && (__builtin_bit_cast(unsigned, hv0[i]) != SENT)
                        && (__builtin_bit_cast(unsigned, hv1[i]) != SENT)
                        && (__builtin_bit_cast(unsigned, hv2[i]) != SENT)
                        && (__builtin_bit_cast(unsigned, hv3[i]) != SENT);
            }
        } while (!ok && ++spins < (1 << 20));   // hang guard
        __builtin_amdgcn_sched_barrier(0);

        // stage -> LDS as bf16 hi/lo (Dekker split), XOR-swizzled
        {
            f4_t hv[4] = {hv0, hv1, hv2, hv3};
            #pragma unroll
            for (int t = 0; t < 4; t++) {
                int idx4 = tid + t * 512;                 // 2048 float4s
                int row = idx4 >> 7, c4 = idx4 & 127;
                us4_t hi, lo;
                #pragma unroll
                for (int i = 0; i < 4; i++) {
                    unsigned short h = f2bf(hv[t][i]);
                    hi[i] = h;
                    lo[i] = f2bf(hv[t][i] - bf2f(h));
                }
                int base = row * 512 + (((c4 >> 1) ^ (row & 7)) << 3) + (c4 & 1) * 4;
                *(us4_t*)(&sHi[base]) = hi;
                *(us4_t*)(&sLo[base]) = lo;
            }
        }
        __syncthreads();

        if (wave < 6) {                       // pre = h @ Wslice.T  (hi+lo accumulate)
            f4_t acc = {0.f, 0.f, 0.f, 0.f};
            const int m = lane & 15;
            #pragma unroll
            for (int kk = 0; kk < 16; kk++) {
                int off = m * 512 + (((kk * 4 + (lane >> 4)) ^ (m & 7)) << 3);
                bf8_t ahi = *(const bf8_t*)(&sHi[off]);
                bf8_t alo = *(const bf8_t*)(&sLo[off]);
                acc = __builtin_amdgcn_mfma_f32_16x16x32_bf16(ahi, wfrag[kk], acc, 0, 0, 0);
                acc = __builtin_amdgcn_mfma_f32_16x16x32_bf16(alo, wfrag[kk], acc, 0, 0, 0);
            }
            const int n = wave * 16 + (lane & 15);
            #pragma unroll
            for (int r = 0; r < 4; r++) sPre[n * 17 + (lane >> 4) * 4 + r] = acc[r];
        }
        __syncthreads();

        // gates: thread owns (b_, jj)
        float r = sigm(gr + sPre[jj * 17 + b_] + brv);
        float z = sigm(gz + sPre[(32 + jj) * 17 + b_] + bzv);
        float nn = tanhf(gn + r * (sPre[(64 + jj) * 17 + b_] + bnv));
        float hnew = (1.f - z) * nn + z * h_reg;
        h_reg = hnew;

        // publish: ONE one-way sc0sc1 store; consumers poll the data directly.
        llc_store_f32(&hbuf[(size_t)s * 8192 + b_ * 512 + j0 + jj], hnew);
        Hout[(size_t)(b_ * 128 + (s - 1)) * 512 + j0 + jj] = f2bf(hnew);  // overlaps next poll
    }
}

extern "C" void kernel_launch(void* const* d_in, const int* in_sizes, int n_in,
                              void* d_out, int out_size, void* d_ws, size_t ws_size,
                              hipStream_t stream) {
    const int*   y      = (const int*)  d_in[0];
    const float* hn     = (const float*)d_in[1];
    const float* emb    = (const float*)d_in[2];
    const float* W_ih   = (const float*)d_in[3];
    const float* W_hh   = (const float*)d_in[4];
    const float* b_ih   = (const float*)d_in[5];
    const float* b_hh   = (const float*)d_in[6];
    const float* fc_w   = (const float*)d_in[7];
    const float* fc_b   = (const float*)d_in[8];
    const float* pred_w = (const float*)d_in[9];
    const float* pred_b = (const float*)d_in[10];
    float* out = (float*)d_out;

    char* ws = (char*)d_ws;
    size_t off = 0;
    auto alloc = [&](size_t bytes) { void* p = ws + off; off = (off + bytes + 255) & ~(size_t)255; return p; };
    float*          hbuf   = (float*)          alloc((size_t)129 * 8192 * 4);  // per-step h buffers
    float*          gx     = (float*)          alloc((size_t)2048 * 1536 * 4);
    unsigned short* Hout   = (unsigned short*) alloc((size_t)2048 * 512 * 2);
    unsigned short* xbf    = (unsigned short*) alloc((size_t)2048 * 512 * 2);
    unsigned short* wihbf  = (unsigned short*) alloc((size_t)1536 * 512 * 2);
    unsigned short* pwbf   = (unsigned short*) alloc((size_t)32000 * 512 * 2);
    (void)ws_size; (void)in_sizes; (void)n_in; (void)out_size;                 // ~55 MB used

    k_fill  <<<1032, 256, 0, stream>>>((unsigned int*)hbuf);        // 129*8192 floats = 264192 u4s
    k_conv  <<<4096, 256, 0, stream>>>(pred_w, pwbf, 32000 * 512 / 4);
    k_conv  <<<512,  256, 0, stream>>>(W_ih,  wihbf, 1536 * 512 / 4);
    k_gather<<<2048, 128, 0, stream>>>(y, emb, xbf);
    k_h0    <<<16,   256, 0, stream>>>(hn, fc_w, fc_b, hbuf);
    dim3 gG(12, 16);
    k_gemm  <<<gG, 256, 0, stream>>>(xbf, wihbf, b_ih, gx, 1536);
    k_rec   <<<16, 512, 0, stream>>>(W_hh, b_hh, gx, hbuf, Hout);
    dim3 gP(250, 16);
    k_gemm  <<<gP, 256, 0, stream>>>(Hout, pwbf, pred_b, out, 32000);
}